// Round 5
// baseline (386.085 us; speedup 1.0000x reference)
//
#include <hip/hip_runtime.h>
#include <math.h>

typedef __bf16 bf16_t;
typedef __bf16 bf16x8 __attribute__((ext_vector_type(8)));
typedef __bf16 bf16x4 __attribute__((ext_vector_type(4)));
typedef float f32x4 __attribute__((ext_vector_type(4)));

#define N_TOK 4096
#define DMODEL 1024
#define FFN 1024
#define NEXP 8
#define HIST_BLK 16

#define BM 128
#define BN 128
#define BK 32
#define NT 32  // K=1024 / BK

// async global->LDS, 16B per lane, wave-uniform LDS base + lane*16 (ladder step 3)
__device__ __forceinline__ void gload16(const bf16_t* g, bf16_t* l) {
  __builtin_amdgcn_global_load_lds((const __attribute__((address_space(1))) void*)g,
                                   (__attribute__((address_space(3))) void*)l, 16, 0, 0);
}

// ---------------- prep: all weight transposes fp32->bf16 in ONE launch (R3-proven) ----------------
__global__ void transpose_all_kernel(const float* __restrict__ w1, const float* __restrict__ w2,
                                     const float* __restrict__ sgu, const float* __restrict__ sdw,
                                     bf16_t* __restrict__ w1t, bf16_t* __restrict__ w2t,
                                     bf16_t* __restrict__ sgut, bf16_t* __restrict__ sdt) {
  __shared__ float tile[32][33];
  const int z = blockIdx.z;
  const float* in;
  bf16_t* out;
  int C = 1024;
  bool remap = false;
  if (z < 8) {
    in = w1 + (size_t)z * 1048576; out = w1t + (size_t)z * 1048576;
  } else if (z < 16) {
    in = w2 + (size_t)(z - 8) * 1048576; out = w2t + (size_t)(z - 8) * 1048576;
  } else if (z == 16) {
    in = sgu; out = sgut; C = 2048; remap = true;
  } else {
    in = sdw; out = sdt;
  }
  const int R = 1024;
  const int c0 = blockIdx.x * 32, r0 = blockIdx.y * 32;
  if (c0 >= C) return;
  const int tx = threadIdx.x, ty = threadIdx.y;
#pragma unroll
  for (int i = 0; i < 32; i += 8)
    tile[ty + i][tx] = in[(size_t)(r0 + ty + i) * C + (c0 + tx)];
  __syncthreads();
#pragma unroll
  for (int i = 0; i < 32; i += 8) {
    int c = c0 + ty + i;
    int oc = remap ? ((c < FFN) ? 2 * c : 2 * (c - FFN) + 1) : c;
    out[(size_t)oc * R + (r0 + tx)] = (bf16_t)tile[tx][ty + i];
  }
}

// ---------------- router: logits/softmax/top2/sigmoid gate + fused x->bf16 cast ----------------
__global__ void router_kernel(const float* __restrict__ x, const float* __restrict__ rw,
                              const float* __restrict__ gw, bf16_t* __restrict__ xb,
                              int* __restrict__ topi, float* __restrict__ topw,
                              float* __restrict__ sig) {
  const int t = blockIdx.x;
  const int lane = threadIdx.x;  // 64
  const float* xr = x + (size_t)t * DMODEL;
  bf16_t* xbr = xb + (size_t)t * DMODEL;
  float acc[NEXP] = {0.f, 0.f, 0.f, 0.f, 0.f, 0.f, 0.f, 0.f};
  float accg = 0.f;
#pragma unroll
  for (int i = 0; i < 4; i++) {
    const int d = i * 256 + lane * 4;
    float4 xv = *reinterpret_cast<const float4*>(xr + d);
    bf16x4 o;
    o[0] = (bf16_t)xv.x; o[1] = (bf16_t)xv.y; o[2] = (bf16_t)xv.z; o[3] = (bf16_t)xv.w;
    *reinterpret_cast<bf16x4*>(xbr + d) = o;
    const float xs[4] = {xv.x, xv.y, xv.z, xv.w};
#pragma unroll
    for (int j = 0; j < 4; j++) {
      const float4* r = reinterpret_cast<const float4*>(rw + (size_t)(d + j) * NEXP);
      float4 r0 = r[0], r1 = r[1];
      float xj = xs[j];
      acc[0] += xj * r0.x; acc[1] += xj * r0.y; acc[2] += xj * r0.z; acc[3] += xj * r0.w;
      acc[4] += xj * r1.x; acc[5] += xj * r1.y; acc[6] += xj * r1.z; acc[7] += xj * r1.w;
      accg += xj * gw[d + j];
    }
  }
#pragma unroll
  for (int e = 0; e < NEXP; e++)
    for (int s = 32; s > 0; s >>= 1) acc[e] += __shfl_down(acc[e], s, 64);
  for (int s = 32; s > 0; s >>= 1) accg += __shfl_down(accg, s, 64);
  if (lane == 0) {
    float mx = acc[0];
#pragma unroll
    for (int e = 1; e < NEXP; e++) mx = fmaxf(mx, acc[e]);
    float p[NEXP], sum = 0.f;
#pragma unroll
    for (int e = 0; e < NEXP; e++) { p[e] = __expf(acc[e] - mx); sum += p[e]; }
    int i1 = 0;
#pragma unroll
    for (int e = 1; e < NEXP; e++) if (acc[e] > acc[i1]) i1 = e;
    int i2 = (i1 == 0) ? 1 : 0;
#pragma unroll
    for (int e = 0; e < NEXP; e++) if (e != i1 && acc[e] > acc[i2]) i2 = e;
    float inv = 1.f / sum;
    topi[2 * t] = i1;     topw[2 * t] = p[i1] * inv;
    topi[2 * t + 1] = i2; topw[2 * t + 1] = p[i2] * inv;
    sig[t] = 1.f / (1.f + __expf(-accg));
  }
}

// ---------------- per-block expert histogram (LDS only) ----------------
__global__ void hist_kernel(const int* __restrict__ topi, int* __restrict__ block_counts) {
  __shared__ int h[NEXP];
  const int tid = threadIdx.x;
  if (tid < NEXP) h[tid] = 0;
  __syncthreads();
  const int t = blockIdx.x * 256 + tid;
  atomicAdd(&h[topi[2 * t]], 1);
  atomicAdd(&h[topi[2 * t + 1]], 1);
  __syncthreads();
  if (tid < NEXP) block_counts[blockIdx.x * NEXP + tid] = h[tid];
}

// ---------------- gather (scan fused; R5-proven) ----------------
__global__ void gather_kernel(const int* __restrict__ topi, const float* __restrict__ topw,
                              const int* __restrict__ block_counts, int* __restrict__ slot_tok,
                              float* __restrict__ slot_w, int* __restrict__ slot_of,
                              int* __restrict__ offsets, int* __restrict__ counts) {
  __shared__ int cur[NEXP];
  const int tid = threadIdx.x;
  if (tid < NEXP) {
    int off = 0;
    for (int f = 0; f < tid; f++)
      for (int b = 0; b < HIST_BLK; b++) off += block_counts[b * NEXP + f];
    int bb = off;
    for (int b = 0; b < (int)blockIdx.x; b++) bb += block_counts[b * NEXP + tid];
    cur[tid] = bb;
    if (blockIdx.x == 0) {
      offsets[tid] = off;
      int tot = 0;
      for (int b = 0; b < HIST_BLK; b++) tot += block_counts[b * NEXP + tid];
      counts[tid] = tot;
    }
  }
  __syncthreads();
  const int t = blockIdx.x * 256 + tid;
#pragma unroll
  for (int j = 0; j < 2; j++) {
    int e = topi[2 * t + j];
    int s = atomicAdd(&cur[e], 1);
    slot_tok[s] = t;
    slot_w[s] = topw[2 * t + j];
    slot_of[2 * t + j] = s;
  }
}

// ---------------- combine: out[t] += Y[slot0] + Y[slot1] ----------------
__global__ void combine_kernel(const bf16_t* __restrict__ Y, const int* __restrict__ slot_of,
                               float* __restrict__ out) {
  int i = blockIdx.x * blockDim.x + threadIdx.x;
  int t = i >> 7;
  int d = (i & 127) << 3;
  int s0 = slot_of[2 * t], s1 = slot_of[2 * t + 1];
  bf16x8 a = *reinterpret_cast<const bf16x8*>(Y + (size_t)s0 * DMODEL + d);
  bf16x8 b = *reinterpret_cast<const bf16x8*>(Y + (size_t)s1 * DMODEL + d);
  float* o = out + (size_t)t * DMODEL + d;
  float4 o0 = *reinterpret_cast<float4*>(o);
  float4 o1 = *reinterpret_cast<float4*>(o + 4);
  o0.x += (float)a[0] + (float)b[0]; o0.y += (float)a[1] + (float)b[1];
  o0.z += (float)a[2] + (float)b[2]; o0.w += (float)a[3] + (float)b[3];
  o1.x += (float)a[4] + (float)b[4]; o1.y += (float)a[5] + (float)b[5];
  o1.z += (float)a[6] + (float)b[6]; o1.w += (float)a[7] + (float)b[7];
  *reinterpret_cast<float4*>(o) = o0;
  *reinterpret_cast<float4*>(o + 4) = o1;
}

// ---------------- MFMA GEMM, 128x128 tile — R9: depth-3 ring pipeline + XCD swizzle ------------
// R8 post-mortem: dynamic lds[cur] -> compiler may-alias -> vmcnt drain right after stage issue.
// Fix 1 (T3+T4): FOUR separate __shared__ arrays (distinct objects, AA NoAlias), static buffer
//   names via unroll-by-4, counted s_waitcnt vmcnt(12/8/4/0) (4 DMA instrs/stage, 3 stages in
//   flight), raw s_barrier (no drain), sched_barrier(0) fences. Loads get 3 compute phases of
//   latency hiding.
// Fix 2 (T1): transpose-swizzle f=by*gx+bx -> nby=f&31, nbx=f>>5. All blocks sharing an A-panel
//   land on XCD nby%8 -> A-panel fetched once per XCD (A HBM traffic 8x down, mode 0).
// Swizzle (R6-proven involution, key=row&3): phys 16B chunk = logical ^ ((row)&3) pattern via
//   write side (lane&3)^((lane>>3)&3), read side qd^((lm>>1)&3). 0 bank conflicts measured.
// MODE 0: S(bf16) = silu_pair(xb @ sgut interleaved); MODE 1: H = silu(xb[slot_tok] @ w1t[e]);
// MODE 2: Y = slot_w * (H @ w2t[e]); MODE 3: out(f32) = sig * (S @ sdt)
template <int MODE>
__global__ __launch_bounds__(256) void gemm_kernel(
    const bf16_t* __restrict__ A, const bf16_t* __restrict__ B, void* __restrict__ Cout,
    int N, const int* __restrict__ offsets, const int* __restrict__ counts,
    const int* __restrict__ slot_tok, const float* __restrict__ slot_w,
    const float* __restrict__ sig) {
  __shared__ bf16_t ldsb0[(BM + BN) * BK];  // 16 KB each; 4 distinct objects so the
  __shared__ bf16_t ldsb1[(BM + BN) * BK];  // waitcnt pass proves DMA-vs-ds_read NoAlias
  __shared__ bf16_t ldsb2[(BM + BN) * BK];
  __shared__ bf16_t ldsb3[(BM + BN) * BK];

  // XCD transpose-swizzle: same-nby blocks -> same XCD -> A-panel L2-resident
  const int f = (int)blockIdx.y * (int)gridDim.x + (int)blockIdx.x;
  const int nby = f & 31;   // gridDim.y == 32 in all gemm launches
  const int nbx = f >> 5;

  const int e = blockIdx.z;
  int m0, mEnd;
  const bf16_t* Bp = B;
  if (MODE == 1 || MODE == 2) {
    const int off = offsets[e], cnt = counts[e];
    m0 = off + nby * BM;
    mEnd = off + cnt;
    if (m0 >= mEnd) return;
    Bp += (size_t)e * FFN * DMODEL;
  } else {
    m0 = nby * BM;
    mEnd = N_TOK;
  }
  const int n0 = nbx * BN;

  const int tid = threadIdx.x;
  const int lane = tid & 63;
  const int wave = tid >> 6;
  const int wm = (wave >> 1) * 64;
  const int wn = (wave & 1) * 64;
  const int qd = lane >> 4;
  const int lm = lane & 15;

  // staging: lane owns row (wave*16 + lane>>2) (+64 for h=1), physical 16B chunk (lane&3);
  // it FETCHES logical chunk (lane&3)^((lane>>3)&3)  [both-sides involution, R6-proven]
  const int srow = wave * 16 + (lane >> 2);
  const int chunk = (lane & 3) ^ ((lane >> 3) & 3);
  int s0r = m0 + srow, s1r = m0 + srow + 64;
  int sc0 = (s0r < mEnd) ? s0r : (mEnd - 1);
  int sc1 = (s1r < mEnd) ? s1r : (mEnd - 1);
  int g0, g1;
  if (MODE == 1) { g0 = slot_tok[sc0]; g1 = slot_tok[sc1]; }
  else if (MODE == 2) { g0 = sc0; g1 = sc1; }
  else { g0 = s0r; g1 = s1r; }
  const bf16_t* pa0 = A + (size_t)g0 * 1024 + chunk * 8;
  const bf16_t* pa1 = A + (size_t)g1 * 1024 + chunk * 8;
  const bf16_t* pb0 = Bp + (size_t)(n0 + srow) * 1024 + chunk * 8;
  const bf16_t* pb1 = Bp + (size_t)(n0 + srow + 64) * 1024 + chunk * 8;

  f32x4 acc[4][4] = {};
  const int pcr = qd ^ ((lm >> 1) & 3);  // read-side phys chunk (swizzle involution)

#define SBAR0 __builtin_amdgcn_sched_barrier(0)
  // 4 global_load_lds_dwordx4 per STAGE (one vmcnt unit each)
#define STAGE(LDSB, T)                                          \
  do {                                                          \
    const int k0s = (T) * BK;                                   \
    gload16(pa0 + k0s, &LDSB[(wave * 16) * BK]);                \
    gload16(pa1 + k0s, &LDSB[(64 + wave * 16) * BK]);           \
    gload16(pb0 + k0s, &LDSB[(BM + wave * 16) * BK]);           \
    gload16(pb1 + k0s, &LDSB[(BM + 64 + wave * 16) * BK]);      \
  } while (0)

#define COMPUTE(LDSB)                                                        \
  do {                                                                       \
    bf16x8 af[4], bfr[4];                                                    \
    _Pragma("unroll") for (int i = 0; i < 4; i++)                            \
        af[i] = *reinterpret_cast<const bf16x8*>(                            \
            &LDSB[(wm + i * 16 + lm) * BK + pcr * 8]);                       \
    _Pragma("unroll") for (int j = 0; j < 4; j++)                            \
        bfr[j] = *reinterpret_cast<const bf16x8*>(                           \
            &LDSB[(BM + wn + j * 16 + lm) * BK + pcr * 8]);                  \
    _Pragma("unroll") for (int i = 0; i < 4; i++)                            \
        _Pragma("unroll") for (int j = 0; j < 4; j++)                        \
            acc[i][j] = __builtin_amdgcn_mfma_f32_16x16x32_bf16(             \
                af[i], bfr[j], acc[i][j], 0, 0, 0);                          \
  } while (0)

  // ITER: [stage next | counted vmcnt | barrier | compute | barrier], fences at phase edges
#define ITER_S(T, CBUF, PBUF, WAIT)       \
  do {                                    \
    STAGE(PBUF, (T) + 3);                 \
    SBAR0;                                \
    asm volatile(WAIT ::: "memory");      \
    __builtin_amdgcn_s_barrier();         \
    SBAR0;                                \
    COMPUTE(CBUF);                        \
    SBAR0;                                \
    __builtin_amdgcn_s_barrier();         \
    SBAR0;                                \
  } while (0)
#define ITER_N(CBUF, WAIT)                \
  do {                                    \
    SBAR0;                                \
    asm volatile(WAIT ::: "memory");      \
    __builtin_amdgcn_s_barrier();         \
    SBAR0;                                \
    COMPUTE(CBUF);                        \
    SBAR0;                                \
    __builtin_amdgcn_s_barrier();         \
    SBAR0;                                \
  } while (0)

  // prologue: tiles 0,1,2 -> buffers 0,1,2 (12 loads in flight)
  STAGE(ldsb0, 0);
  STAGE(ldsb1, 1);
  STAGE(ldsb2, 2);

  // main: T=0..27, always stage T+3, steady-state 12 outstanding after issue
  for (int tt = 0; tt < 28; tt += 4) {
    ITER_S(tt + 0, ldsb0, ldsb3, "s_waitcnt vmcnt(12)");
    ITER_S(tt + 1, ldsb1, ldsb0, "s_waitcnt vmcnt(12)");
    ITER_S(tt + 2, ldsb2, ldsb1, "s_waitcnt vmcnt(12)");
    ITER_S(tt + 3, ldsb3, ldsb2, "s_waitcnt vmcnt(12)");
  }
  // T=28 stages tile 31; 29..31 drain 8/4/0
  ITER_S(28, ldsb0, ldsb3, "s_waitcnt vmcnt(12)");
  ITER_N(ldsb1, "s_waitcnt vmcnt(8)");
  ITER_N(ldsb2, "s_waitcnt vmcnt(4)");
  ITER_N(ldsb3, "s_waitcnt vmcnt(0)");

#undef ITER_N
#undef ITER_S
#undef COMPUTE
#undef STAGE
#undef SBAR0

  // epilogue: C row = (lane>>4)*4 + reg, col = lane&15  [HW-verified]
#pragma unroll
  for (int i = 0; i < 4; i++) {
#pragma unroll
    for (int r = 0; r < 4; r++) {
      const int gm = m0 + wm + i * 16 + qd * 4 + r;
      const bool mOk = (MODE == 0 || MODE == 3) || (gm < mEnd);
      const float wgt = (MODE == 2 && mOk) ? slot_w[gm] : 0.f;
#pragma unroll
      for (int j = 0; j < 4; j++) {
        const int col = n0 + wn + j * 16 + lm;
        float v = acc[i][j][r];
        if (MODE == 0) {
          // cols interleaved: even = gate f, odd = up f (f = col>>1); pair via shfl_xor
          float u = __shfl_xor(v, 1, 64);
          if ((lane & 1) == 0) {
            float sv = v / (1.f + __expf(-v)) * u;
            ((bf16_t*)Cout)[(size_t)gm * FFN + (col >> 1)] = (bf16_t)sv;
          }
        } else if (MODE == 1) {
          if (mOk) ((bf16_t*)Cout)[(size_t)gm * FFN + col] = (bf16_t)(v / (1.f + __expf(-v)));
        } else if (MODE == 2) {
          if (mOk) ((bf16_t*)Cout)[(size_t)gm * DMODEL + col] = (bf16_t)(wgt * v);
        } else {
          ((float*)Cout)[(size_t)gm * DMODEL + col] = sig[gm] * v;
        }
      }
    }
  }
}

extern "C" void kernel_launch(void* const* d_in, const int* in_sizes, int n_in, void* d_out,
                              int out_size, void* d_ws, size_t ws_size, hipStream_t stream) {
  const float* x = (const float*)d_in[0];
  const float* rw = (const float*)d_in[1];
  const float* w1 = (const float*)d_in[2];
  const float* w2 = (const float*)d_in[3];
  const float* sgu = (const float*)d_in[4];
  const float* sdw = (const float*)d_in[5];
  const float* gw = (const float*)d_in[6];
  float* out = (float*)d_out;

  char* ws = (char*)d_ws;
  size_t off = 0;
  auto alloc = [&](size_t bytes) -> void* {
    void* p = ws + off;
    off += (bytes + 255) & ~(size_t)255;
    return p;
  };
  bf16_t* xb = (bf16_t*)alloc((size_t)N_TOK * DMODEL * 2);
  bf16_t* w1t = (bf16_t*)alloc((size_t)NEXP * DMODEL * FFN * 2);
  bf16_t* w2t = (bf16_t*)alloc((size_t)NEXP * DMODEL * FFN * 2);
  bf16_t* sgut = (bf16_t*)alloc((size_t)2 * FFN * DMODEL * 2);  // rows gate/up interleaved
  bf16_t* sdt = (bf16_t*)alloc((size_t)DMODEL * FFN * 2);
  bf16_t* S = (bf16_t*)alloc((size_t)N_TOK * FFN * 2);
  bf16_t* H = (bf16_t*)alloc((size_t)N_TOK * 2 * FFN * 2);    // slot-major
  bf16_t* Y = (bf16_t*)alloc((size_t)N_TOK * 2 * DMODEL * 2); // slot-major
  int* topi = (int*)alloc(N_TOK * 2 * 4);
  float* topw = (float*)alloc(N_TOK * 2 * 4);
  float* sig = (float*)alloc(N_TOK * 4);
  int* slot_tok = (int*)alloc(N_TOK * 2 * 4);
  float* slot_w = (float*)alloc(N_TOK * 2 * 4);
  int* slot_of = (int*)alloc(N_TOK * 2 * 4);
  int* block_counts = (int*)alloc(HIST_BLK * NEXP * 4);
  int* counts = (int*)alloc(NEXP * 4);
  int* offsets = (int*)alloc(NEXP * 4);

  // prep + routing (R1-proven 4-launch structure)
  transpose_all_kernel<<<dim3(64, 32, 18), dim3(32, 8), 0, stream>>>(w1, w2, sgu, sdw, w1t, w2t,
                                                                     sgut, sdt);
  router_kernel<<<N_TOK, 64, 0, stream>>>(x, rw, gw, xb, topi, topw, sig);
  hist_kernel<<<HIST_BLK, 256, 0, stream>>>(topi, block_counts);
  gather_kernel<<<HIST_BLK, 256, 0, stream>>>(topi, topw, block_counts, slot_tok, slot_w,
                                              slot_of, offsets, counts);

  // shared up (silu fused into epilogue): S = silu(gate)*up
  gemm_kernel<0><<<dim3(2 * FFN / BN, N_TOK / BM, 1), 256, 0, stream>>>(
      xb, sgut, S, 2 * FFN, nullptr, nullptr, nullptr, nullptr, nullptr);
  // expert up: H = silu(xb[tok] @ w1t[e])
  gemm_kernel<1><<<dim3(FFN / BN, N_TOK / BM, NEXP), 256, 0, stream>>>(
      xb, w1t, H, FFN, offsets, counts, slot_tok, nullptr, nullptr);
  // expert down: Y = slot_w * (H @ w2t[e])
  gemm_kernel<2><<<dim3(DMODEL / BN, N_TOK / BM, NEXP), 256, 0, stream>>>(
      H, w2t, Y, DMODEL, offsets, counts, slot_tok, slot_w, nullptr);
  // shared down: out = sig * (S @ sdt)  (initializes d_out)
  gemm_kernel<3><<<dim3(DMODEL / BN, N_TOK / BM, 1), 256, 0, stream>>>(
      S, sdt, out, DMODEL, nullptr, nullptr, nullptr, nullptr, sig);
  // routed combine
  combine_kernel<<<N_TOK * DMODEL / 8 / 256, 256, 0, stream>>>(Y, slot_of, out);
}

// Round 6
// 298.547 us; speedup vs baseline: 1.2932x; 1.2932x over previous
//
#include <hip/hip_runtime.h>
#include <math.h>

typedef __bf16 bf16_t;
typedef __bf16 bf16x8 __attribute__((ext_vector_type(8)));
typedef __bf16 bf16x4 __attribute__((ext_vector_type(4)));
typedef float f32x4 __attribute__((ext_vector_type(4)));

#define N_TOK 4096
#define DMODEL 1024
#define FFN 1024
#define NEXP 8
#define HIST_BLK 16

#define BM 64   // R10: halved M-tile -> 2x-4x grid -> 4 blocks/CU (TLP hides load latency, m114)
#define BN 128
#define BK 32

// async global->LDS, 16B per lane, wave-uniform LDS base + lane*16 (ladder step 3)
__device__ __forceinline__ void gload16(const bf16_t* g, bf16_t* l) {
  __builtin_amdgcn_global_load_lds((const __attribute__((address_space(1))) void*)g,
                                   (__attribute__((address_space(3))) void*)l, 16, 0, 0);
}

// ---------------- prep: all weight transposes fp32->bf16 in ONE launch (R3-proven) ----------------
__global__ void transpose_all_kernel(const float* __restrict__ w1, const float* __restrict__ w2,
                                     const float* __restrict__ sgu, const float* __restrict__ sdw,
                                     bf16_t* __restrict__ w1t, bf16_t* __restrict__ w2t,
                                     bf16_t* __restrict__ sgut, bf16_t* __restrict__ sdt) {
  __shared__ float tile[32][33];
  const int z = blockIdx.z;
  const float* in;
  bf16_t* out;
  int C = 1024;
  bool remap = false;
  if (z < 8) {
    in = w1 + (size_t)z * 1048576; out = w1t + (size_t)z * 1048576;
  } else if (z < 16) {
    in = w2 + (size_t)(z - 8) * 1048576; out = w2t + (size_t)(z - 8) * 1048576;
  } else if (z == 16) {
    in = sgu; out = sgut; C = 2048; remap = true;
  } else {
    in = sdw; out = sdt;
  }
  const int R = 1024;
  const int c0 = blockIdx.x * 32, r0 = blockIdx.y * 32;
  if (c0 >= C) return;
  const int tx = threadIdx.x, ty = threadIdx.y;
#pragma unroll
  for (int i = 0; i < 32; i += 8)
    tile[ty + i][tx] = in[(size_t)(r0 + ty + i) * C + (c0 + tx)];
  __syncthreads();
#pragma unroll
  for (int i = 0; i < 32; i += 8) {
    int c = c0 + ty + i;
    int oc = remap ? ((c < FFN) ? 2 * c : 2 * (c - FFN) + 1) : c;
    out[(size_t)oc * R + (r0 + tx)] = (bf16_t)tile[tx][ty + i];
  }
}

// ---------------- router: logits/softmax/top2/sigmoid gate + fused x->bf16 cast ----------------
__global__ void router_kernel(const float* __restrict__ x, const float* __restrict__ rw,
                              const float* __restrict__ gw, bf16_t* __restrict__ xb,
                              int* __restrict__ topi, float* __restrict__ topw,
                              float* __restrict__ sig) {
  const int t = blockIdx.x;
  const int lane = threadIdx.x;  // 64
  const float* xr = x + (size_t)t * DMODEL;
  bf16_t* xbr = xb + (size_t)t * DMODEL;
  float acc[NEXP] = {0.f, 0.f, 0.f, 0.f, 0.f, 0.f, 0.f, 0.f};
  float accg = 0.f;
#pragma unroll
  for (int i = 0; i < 4; i++) {
    const int d = i * 256 + lane * 4;
    float4 xv = *reinterpret_cast<const float4*>(xr + d);
    bf16x4 o;
    o[0] = (bf16_t)xv.x; o[1] = (bf16_t)xv.y; o[2] = (bf16_t)xv.z; o[3] = (bf16_t)xv.w;
    *reinterpret_cast<bf16x4*>(xbr + d) = o;
    const float xs[4] = {xv.x, xv.y, xv.z, xv.w};
#pragma unroll
    for (int j = 0; j < 4; j++) {
      const float4* r = reinterpret_cast<const float4*>(rw + (size_t)(d + j) * NEXP);
      float4 r0 = r[0], r1 = r[1];
      float xj = xs[j];
      acc[0] += xj * r0.x; acc[1] += xj * r0.y; acc[2] += xj * r0.z; acc[3] += xj * r0.w;
      acc[4] += xj * r1.x; acc[5] += xj * r1.y; acc[6] += xj * r1.z; acc[7] += xj * r1.w;
      accg += xj * gw[d + j];
    }
  }
#pragma unroll
  for (int e = 0; e < NEXP; e++)
    for (int s = 32; s > 0; s >>= 1) acc[e] += __shfl_down(acc[e], s, 64);
  for (int s = 32; s > 0; s >>= 1) accg += __shfl_down(accg, s, 64);
  if (lane == 0) {
    float mx = acc[0];
#pragma unroll
    for (int e = 1; e < NEXP; e++) mx = fmaxf(mx, acc[e]);
    float p[NEXP], sum = 0.f;
#pragma unroll
    for (int e = 0; e < NEXP; e++) { p[e] = __expf(acc[e] - mx); sum += p[e]; }
    int i1 = 0;
#pragma unroll
    for (int e = 1; e < NEXP; e++) if (acc[e] > acc[i1]) i1 = e;
    int i2 = (i1 == 0) ? 1 : 0;
#pragma unroll
    for (int e = 0; e < NEXP; e++) if (e != i1 && acc[e] > acc[i2]) i2 = e;
    float inv = 1.f / sum;
    topi[2 * t] = i1;     topw[2 * t] = p[i1] * inv;
    topi[2 * t + 1] = i2; topw[2 * t + 1] = p[i2] * inv;
    sig[t] = 1.f / (1.f + __expf(-accg));
  }
}

// ---------------- per-block expert histogram (LDS only) ----------------
__global__ void hist_kernel(const int* __restrict__ topi, int* __restrict__ block_counts) {
  __shared__ int h[NEXP];
  const int tid = threadIdx.x;
  if (tid < NEXP) h[tid] = 0;
  __syncthreads();
  const int t = blockIdx.x * 256 + tid;
  atomicAdd(&h[topi[2 * t]], 1);
  atomicAdd(&h[topi[2 * t + 1]], 1);
  __syncthreads();
  if (tid < NEXP) block_counts[blockIdx.x * NEXP + tid] = h[tid];
}

// ---------------- gather (scan fused; R5-proven) ----------------
__global__ void gather_kernel(const int* __restrict__ topi, const float* __restrict__ topw,
                              const int* __restrict__ block_counts, int* __restrict__ slot_tok,
                              float* __restrict__ slot_w, int* __restrict__ slot_of,
                              int* __restrict__ offsets, int* __restrict__ counts) {
  __shared__ int cur[NEXP];
  const int tid = threadIdx.x;
  if (tid < NEXP) {
    int off = 0;
    for (int f = 0; f < tid; f++)
      for (int b = 0; b < HIST_BLK; b++) off += block_counts[b * NEXP + f];
    int bb = off;
    for (int b = 0; b < (int)blockIdx.x; b++) bb += block_counts[b * NEXP + tid];
    cur[tid] = bb;
    if (blockIdx.x == 0) {
      offsets[tid] = off;
      int tot = 0;
      for (int b = 0; b < HIST_BLK; b++) tot += block_counts[b * NEXP + tid];
      counts[tid] = tot;
    }
  }
  __syncthreads();
  const int t = blockIdx.x * 256 + tid;
#pragma unroll
  for (int j = 0; j < 2; j++) {
    int e = topi[2 * t + j];
    int s = atomicAdd(&cur[e], 1);
    slot_tok[s] = t;
    slot_w[s] = topw[2 * t + j];
    slot_of[2 * t + j] = s;
  }
}

// ---------------- combine: out[t] += Y[slot0] + Y[slot1] ----------------
__global__ void combine_kernel(const bf16_t* __restrict__ Y, const int* __restrict__ slot_of,
                               float* __restrict__ out) {
  int i = blockIdx.x * blockDim.x + threadIdx.x;
  int t = i >> 7;
  int d = (i & 127) << 3;
  int s0 = slot_of[2 * t], s1 = slot_of[2 * t + 1];
  bf16x8 a = *reinterpret_cast<const bf16x8*>(Y + (size_t)s0 * DMODEL + d);
  bf16x8 b = *reinterpret_cast<const bf16x8*>(Y + (size_t)s1 * DMODEL + d);
  float* o = out + (size_t)t * DMODEL + d;
  float4 o0 = *reinterpret_cast<float4*>(o);
  float4 o1 = *reinterpret_cast<float4*>(o + 4);
  o0.x += (float)a[0] + (float)b[0]; o0.y += (float)a[1] + (float)b[1];
  o0.z += (float)a[2] + (float)b[2]; o0.w += (float)a[3] + (float)b[3];
  o1.x += (float)a[4] + (float)b[4]; o1.y += (float)a[5] + (float)b[5];
  o1.z += (float)a[6] + (float)b[6]; o1.w += (float)a[7] + (float)b[7];
  *reinterpret_cast<float4*>(o) = o0;
  *reinterpret_cast<float4*>(o + 4) = o1;
}

// ---------------- MFMA GEMM, 64x128 tile — R10: smaller tile for TLP ---------------------------
// R9 post-mortem: XCD swizzle thrashed per-XCD L2 (FETCH 49.5->73 MB, reverted); hand-scheduled
// ring serialized worse than compiler schedule (guide common-mistake #5, reverted).
// R10: EXACT R6 loop (proven: 0 conflicts, 39.7us @ 128x128) but BM 128->64:
//   grid 512 -> 1024-4096 blocks = 4 blocks/CU; m114 wave-level overlap hides the per-iter
//   vmcnt drain via TLP instead of source-level pipelining. LDS 12 KB, acc 2x4.
// Swizzle (R6-proven involution): phys 16B chunk = logical ^ ((row>>1)&3).
//   write side: lane owns row wave*16+(lane>>2), phys chunk lane&3, fetches logical
//               (lane&3)^((lane>>3)&3); read side: phys = qd^((lm>>1)&3). 0 conflicts measured.
// Wave tiling: wm=(wave>>1)*32, wn=(wave&1)*64 -> each wave 32x64 = acc[2][4].
// MODE 0: S(bf16) = silu_pair(xb @ sgut interleaved)  [N=2048 cols -> 1024 via lane pairs]
// MODE 1: H(bf16) = silu(xb[slot_tok] @ w1t[e])
// MODE 2: Y(bf16) = slot_w * (H @ w2t[e])
// MODE 3: out(f32) = sig[m] * (S @ sdt)   (initializes d_out)
template <int MODE>
__global__ __launch_bounds__(256) void gemm_kernel(
    const bf16_t* __restrict__ A, const bf16_t* __restrict__ B, void* __restrict__ Cout,
    int N, const int* __restrict__ offsets, const int* __restrict__ counts,
    const int* __restrict__ slot_tok, const float* __restrict__ slot_w,
    const float* __restrict__ sig) {
  __shared__ bf16_t lds_a[BM * BK];  // 4 KB
  __shared__ bf16_t lds_b[BN * BK];  // 8 KB

  const int e = blockIdx.z;
  int m0, mEnd;
  const bf16_t* Bp = B;
  if (MODE == 1 || MODE == 2) {
    const int off = offsets[e], cnt = counts[e];
    m0 = off + (int)blockIdx.y * BM;
    mEnd = off + cnt;
    if (m0 >= mEnd) return;
    Bp += (size_t)e * FFN * DMODEL;
  } else {
    m0 = blockIdx.y * BM;
    mEnd = N_TOK;
  }
  const int n0 = blockIdx.x * BN;

  const int tid = threadIdx.x;
  const int lane = tid & 63;
  const int wave = tid >> 6;
  const int wm = (wave >> 1) * 32;
  const int wn = (wave & 1) * 64;
  const int qd = lane >> 4;
  const int lm = lane & 15;

  // staging: lane owns row wave*16 + (lane>>2) of each 64-row group, physical 16B chunk (lane&3);
  // it FETCHES logical chunk (lane&3)^((lane>>3)&3)  [both-sides involution, R6-proven]
  const int srow = wave * 16 + (lane >> 2);
  const int chunk = (lane & 3) ^ ((lane >> 3) & 3);
  int sA = m0 + srow;
  int scA = (sA < mEnd) ? sA : (mEnd - 1);
  int g;
  if (MODE == 1) g = slot_tok[scA];
  else if (MODE == 2) g = scA;
  else g = sA;
  const bf16_t* pa = A + (size_t)g * 1024 + chunk * 8;  // K = 1024 all modes
  const bf16_t* pb0 = Bp + (size_t)(n0 + srow) * 1024 + chunk * 8;
  const bf16_t* pb1 = Bp + (size_t)(n0 + srow + 64) * 1024 + chunk * 8;
  // wave-uniform LDS bases for the async DMA (dest = base + lane*16B)
  bf16_t* la = &lds_a[(wave * 16) * BK];
  bf16_t* lb0 = &lds_b[(wave * 16) * BK];
  bf16_t* lb1 = &lds_b[(64 + wave * 16) * BK];

  f32x4 acc[2][4] = {};

  const int pcr = qd ^ ((lm >> 1) & 3);  // read-side phys chunk (swizzle involution)

  for (int k0 = 0; k0 < 1024; k0 += BK) {
    __syncthreads();  // previous-iter reads done before overwrite
    gload16(pa + k0, la);
    gload16(pb0 + k0, lb0);
    gload16(pb1 + k0, lb1);
    __syncthreads();  // vmcnt(0) drained before barrier -> LDS ready
    bf16x8 af[2], bfr[4];
#pragma unroll
    for (int i = 0; i < 2; i++)
      af[i] = *reinterpret_cast<const bf16x8*>(&lds_a[(wm + i * 16 + lm) * BK + pcr * 8]);
#pragma unroll
    for (int j = 0; j < 4; j++)
      bfr[j] = *reinterpret_cast<const bf16x8*>(&lds_b[(wn + j * 16 + lm) * BK + pcr * 8]);
#pragma unroll
    for (int i = 0; i < 2; i++)
#pragma unroll
      for (int j = 0; j < 4; j++)
        acc[i][j] = __builtin_amdgcn_mfma_f32_16x16x32_bf16(af[i], bfr[j], acc[i][j], 0, 0, 0);
  }

  // epilogue: C row = (lane>>4)*4 + reg, col = lane&15  [HW-verified]
#pragma unroll
  for (int i = 0; i < 2; i++) {
#pragma unroll
    for (int r = 0; r < 4; r++) {
      const int gm = m0 + wm + i * 16 + qd * 4 + r;
      const bool mOk = (MODE == 0 || MODE == 3) || (gm < mEnd);
      const float wgt = (MODE == 2 && mOk) ? slot_w[gm] : 0.f;
#pragma unroll
      for (int j = 0; j < 4; j++) {
        const int col = n0 + wn + j * 16 + lm;
        float v = acc[i][j][r];
        if (MODE == 0) {
          // cols interleaved: even = gate f, odd = up f (f = col>>1); pair via shfl_xor
          float u = __shfl_xor(v, 1, 64);
          if ((lane & 1) == 0) {
            float sv = v / (1.f + __expf(-v)) * u;
            ((bf16_t*)Cout)[(size_t)gm * FFN + (col >> 1)] = (bf16_t)sv;
          }
        } else if (MODE == 1) {
          if (mOk) ((bf16_t*)Cout)[(size_t)gm * FFN + col] = (bf16_t)(v / (1.f + __expf(-v)));
        } else if (MODE == 2) {
          if (mOk) ((bf16_t*)Cout)[(size_t)gm * DMODEL + col] = (bf16_t)(wgt * v);
        } else {
          ((float*)Cout)[(size_t)gm * DMODEL + col] = sig[gm] * v;
        }
      }
    }
  }
}

extern "C" void kernel_launch(void* const* d_in, const int* in_sizes, int n_in, void* d_out,
                              int out_size, void* d_ws, size_t ws_size, hipStream_t stream) {
  const float* x = (const float*)d_in[0];
  const float* rw = (const float*)d_in[1];
  const float* w1 = (const float*)d_in[2];
  const float* w2 = (const float*)d_in[3];
  const float* sgu = (const float*)d_in[4];
  const float* sdw = (const float*)d_in[5];
  const float* gw = (const float*)d_in[6];
  float* out = (float*)d_out;

  char* ws = (char*)d_ws;
  size_t off = 0;
  auto alloc = [&](size_t bytes) -> void* {
    void* p = ws + off;
    off += (bytes + 255) & ~(size_t)255;
    return p;
  };
  bf16_t* xb = (bf16_t*)alloc((size_t)N_TOK * DMODEL * 2);
  bf16_t* w1t = (bf16_t*)alloc((size_t)NEXP * DMODEL * FFN * 2);
  bf16_t* w2t = (bf16_t*)alloc((size_t)NEXP * DMODEL * FFN * 2);
  bf16_t* sgut = (bf16_t*)alloc((size_t)2 * FFN * DMODEL * 2);  // rows gate/up interleaved
  bf16_t* sdt = (bf16_t*)alloc((size_t)DMODEL * FFN * 2);
  bf16_t* S = (bf16_t*)alloc((size_t)N_TOK * FFN * 2);
  bf16_t* H = (bf16_t*)alloc((size_t)N_TOK * 2 * FFN * 2);    // slot-major
  bf16_t* Y = (bf16_t*)alloc((size_t)N_TOK * 2 * DMODEL * 2); // slot-major
  int* topi = (int*)alloc(N_TOK * 2 * 4);
  float* topw = (float*)alloc(N_TOK * 2 * 4);
  float* sig = (float*)alloc(N_TOK * 4);
  int* slot_tok = (int*)alloc(N_TOK * 2 * 4);
  float* slot_w = (float*)alloc(N_TOK * 2 * 4);
  int* slot_of = (int*)alloc(N_TOK * 2 * 4);
  int* block_counts = (int*)alloc(HIST_BLK * NEXP * 4);
  int* counts = (int*)alloc(NEXP * 4);
  int* offsets = (int*)alloc(NEXP * 4);

  // prep + routing (R1-proven structure)
  transpose_all_kernel<<<dim3(64, 32, 18), dim3(32, 8), 0, stream>>>(w1, w2, sgu, sdw, w1t, w2t,
                                                                     sgut, sdt);
  router_kernel<<<N_TOK, 64, 0, stream>>>(x, rw, gw, xb, topi, topw, sig);
  hist_kernel<<<HIST_BLK, 256, 0, stream>>>(topi, block_counts);
  gather_kernel<<<HIST_BLK, 256, 0, stream>>>(topi, topw, block_counts, slot_tok, slot_w,
                                              slot_of, offsets, counts);

  // shared up (silu fused into epilogue): S = silu(gate)*up   [grid 16x64 = 1024 blocks]
  gemm_kernel<0><<<dim3(2 * FFN / BN, N_TOK / BM, 1), 256, 0, stream>>>(
      xb, sgut, S, 2 * FFN, nullptr, nullptr, nullptr, nullptr, nullptr);
  // expert up: H = silu(xb[tok] @ w1t[e])   [y=64 covers worst-case cnt=4096; empties return]
  gemm_kernel<1><<<dim3(FFN / BN, N_TOK / BM, NEXP), 256, 0, stream>>>(
      xb, w1t, H, FFN, offsets, counts, slot_tok, nullptr, nullptr);
  // expert down: Y = slot_w * (H @ w2t[e])
  gemm_kernel<2><<<dim3(DMODEL / BN, N_TOK / BM, NEXP), 256, 0, stream>>>(
      H, w2t, Y, DMODEL, offsets, counts, slot_tok, slot_w, nullptr);
  // shared down: out = sig * (S @ sdt)  (initializes d_out)  [grid 8x64 = 512 blocks, was 256]
  gemm_kernel<3><<<dim3(DMODEL / BN, N_TOK / BM, 1), 256, 0, stream>>>(
      S, sdt, out, DMODEL, nullptr, nullptr, nullptr, nullptr, sig);
  // routed combine
  combine_kernel<<<N_TOK * DMODEL / 8 / 256, 256, 0, stream>>>(Y, slot_of, out);
}

// Round 7
// 279.085 us; speedup vs baseline: 1.3834x; 1.0697x over previous
//
#include <hip/hip_runtime.h>
#include <math.h>

typedef __bf16 bf16_t;
typedef __bf16 bf16x8 __attribute__((ext_vector_type(8)));
typedef __bf16 bf16x4 __attribute__((ext_vector_type(4)));
typedef float f32x4 __attribute__((ext_vector_type(4)));

#define N_TOK 4096
#define DMODEL 1024
#define FFN 1024
#define NEXP 8
#define HIST_BLK 16

#define BM 128
#define BN 128
#define BK 32
#define LDK 32  // linear (global_load_lds needs contiguous dest); conflicts fixed by XOR chunk swizzle

// async global->LDS, 16B per lane, wave-uniform LDS base + lane*16 (ladder step 3)
__device__ __forceinline__ void gload16(const bf16_t* g, bf16_t* l) {
  __builtin_amdgcn_global_load_lds((const __attribute__((address_space(1))) void*)g,
                                   (__attribute__((address_space(3))) void*)l, 16, 0, 0);
}

// ---------------- prep: all weight transposes fp32->bf16 in ONE launch (R3-proven) ----------------
__global__ void transpose_all_kernel(const float* __restrict__ w1, const float* __restrict__ w2,
                                     const float* __restrict__ sgu, const float* __restrict__ sdw,
                                     bf16_t* __restrict__ w1t, bf16_t* __restrict__ w2t,
                                     bf16_t* __restrict__ sgut, bf16_t* __restrict__ sdt) {
  __shared__ float tile[32][33];
  const int z = blockIdx.z;
  const float* in;
  bf16_t* out;
  int C = 1024;
  bool remap = false;
  if (z < 8) {
    in = w1 + (size_t)z * 1048576; out = w1t + (size_t)z * 1048576;
  } else if (z < 16) {
    in = w2 + (size_t)(z - 8) * 1048576; out = w2t + (size_t)(z - 8) * 1048576;
  } else if (z == 16) {
    in = sgu; out = sgut; C = 2048; remap = true;
  } else {
    in = sdw; out = sdt;
  }
  const int R = 1024;
  const int c0 = blockIdx.x * 32, r0 = blockIdx.y * 32;
  if (c0 >= C) return;
  const int tx = threadIdx.x, ty = threadIdx.y;
#pragma unroll
  for (int i = 0; i < 32; i += 8)
    tile[ty + i][tx] = in[(size_t)(r0 + ty + i) * C + (c0 + tx)];
  __syncthreads();
#pragma unroll
  for (int i = 0; i < 32; i += 8) {
    int c = c0 + ty + i;
    int oc = remap ? ((c < FFN) ? 2 * c : 2 * (c - FFN) + 1) : c;
    out[(size_t)oc * R + (r0 + tx)] = (bf16_t)tile[tx][ty + i];
  }
}

// ---------------- router: logits/softmax/top2/sigmoid gate + fused x->bf16 cast ----------------
__global__ void router_kernel(const float* __restrict__ x, const float* __restrict__ rw,
                              const float* __restrict__ gw, bf16_t* __restrict__ xb,
                              int* __restrict__ topi, float* __restrict__ topw,
                              float* __restrict__ sig) {
  const int t = blockIdx.x;
  const int lane = threadIdx.x;  // 64
  const float* xr = x + (size_t)t * DMODEL;
  bf16_t* xbr = xb + (size_t)t * DMODEL;
  float acc[NEXP] = {0.f, 0.f, 0.f, 0.f, 0.f, 0.f, 0.f, 0.f};
  float accg = 0.f;
#pragma unroll
  for (int i = 0; i < 4; i++) {
    const int d = i * 256 + lane * 4;
    float4 xv = *reinterpret_cast<const float4*>(xr + d);
    bf16x4 o;
    o[0] = (bf16_t)xv.x; o[1] = (bf16_t)xv.y; o[2] = (bf16_t)xv.z; o[3] = (bf16_t)xv.w;
    *reinterpret_cast<bf16x4*>(xbr + d) = o;
    const float xs[4] = {xv.x, xv.y, xv.z, xv.w};
#pragma unroll
    for (int j = 0; j < 4; j++) {
      const float4* r = reinterpret_cast<const float4*>(rw + (size_t)(d + j) * NEXP);
      float4 r0 = r[0], r1 = r[1];
      float xj = xs[j];
      acc[0] += xj * r0.x; acc[1] += xj * r0.y; acc[2] += xj * r0.z; acc[3] += xj * r0.w;
      acc[4] += xj * r1.x; acc[5] += xj * r1.y; acc[6] += xj * r1.z; acc[7] += xj * r1.w;
      accg += xj * gw[d + j];
    }
  }
#pragma unroll
  for (int e = 0; e < NEXP; e++)
    for (int s = 32; s > 0; s >>= 1) acc[e] += __shfl_down(acc[e], s, 64);
  for (int s = 32; s > 0; s >>= 1) accg += __shfl_down(accg, s, 64);
  if (lane == 0) {
    float mx = acc[0];
#pragma unroll
    for (int e = 1; e < NEXP; e++) mx = fmaxf(mx, acc[e]);
    float p[NEXP], sum = 0.f;
#pragma unroll
    for (int e = 0; e < NEXP; e++) { p[e] = __expf(acc[e] - mx); sum += p[e]; }
    int i1 = 0;
#pragma unroll
    for (int e = 1; e < NEXP; e++) if (acc[e] > acc[i1]) i1 = e;
    int i2 = (i1 == 0) ? 1 : 0;
#pragma unroll
    for (int e = 0; e < NEXP; e++) if (e != i1 && acc[e] > acc[i2]) i2 = e;
    float inv = 1.f / sum;
    topi[2 * t] = i1;     topw[2 * t] = p[i1] * inv;
    topi[2 * t + 1] = i2; topw[2 * t + 1] = p[i2] * inv;
    sig[t] = 1.f / (1.f + __expf(-accg));
  }
}

// ---------------- per-block expert histogram (LDS only) ----------------
__global__ void hist_kernel(const int* __restrict__ topi, int* __restrict__ block_counts) {
  __shared__ int h[NEXP];
  const int tid = threadIdx.x;
  if (tid < NEXP) h[tid] = 0;
  __syncthreads();
  const int t = blockIdx.x * 256 + tid;
  atomicAdd(&h[topi[2 * t]], 1);
  atomicAdd(&h[topi[2 * t + 1]], 1);
  __syncthreads();
  if (tid < NEXP) block_counts[blockIdx.x * NEXP + tid] = h[tid];
}

// ---------------- gather (scan fused; R5-proven) ----------------
__global__ void gather_kernel(const int* __restrict__ topi, const float* __restrict__ topw,
                              const int* __restrict__ block_counts, int* __restrict__ slot_tok,
                              float* __restrict__ slot_w, int* __restrict__ slot_of,
                              int* __restrict__ offsets, int* __restrict__ counts) {
  __shared__ int cur[NEXP];
  const int tid = threadIdx.x;
  if (tid < NEXP) {
    int off = 0;
    for (int f = 0; f < tid; f++)
      for (int b = 0; b < HIST_BLK; b++) off += block_counts[b * NEXP + f];
    int bb = off;
    for (int b = 0; b < (int)blockIdx.x; b++) bb += block_counts[b * NEXP + tid];
    cur[tid] = bb;
    if (blockIdx.x == 0) {
      offsets[tid] = off;
      int tot = 0;
      for (int b = 0; b < HIST_BLK; b++) tot += block_counts[b * NEXP + tid];
      counts[tid] = tot;
    }
  }
  __syncthreads();
  const int t = blockIdx.x * 256 + tid;
#pragma unroll
  for (int j = 0; j < 2; j++) {
    int e = topi[2 * t + j];
    int s = atomicAdd(&cur[e], 1);
    slot_tok[s] = t;
    slot_w[s] = topw[2 * t + j];
    slot_of[2 * t + j] = s;
  }
}

// ---------------- combine: out[t] += Y[slot0] + Y[slot1] ----------------
__global__ void combine_kernel(const bf16_t* __restrict__ Y, const int* __restrict__ slot_of,
                               float* __restrict__ out) {
  int i = blockIdx.x * blockDim.x + threadIdx.x;
  int t = i >> 7;
  int d = (i & 127) << 3;
  int s0 = slot_of[2 * t], s1 = slot_of[2 * t + 1];
  bf16x8 a = *reinterpret_cast<const bf16x8*>(Y + (size_t)s0 * DMODEL + d);
  bf16x8 b = *reinterpret_cast<const bf16x8*>(Y + (size_t)s1 * DMODEL + d);
  float* o = out + (size_t)t * DMODEL + d;
  float4 o0 = *reinterpret_cast<float4*>(o);
  float4 o1 = *reinterpret_cast<float4*>(o + 4);
  o0.x += (float)a[0] + (float)b[0]; o0.y += (float)a[1] + (float)b[1];
  o0.z += (float)a[2] + (float)b[2]; o0.w += (float)a[3] + (float)b[3];
  o1.x += (float)a[4] + (float)b[4]; o1.y += (float)a[5] + (float)b[5];
  o1.z += (float)a[6] + (float)b[6]; o1.w += (float)a[7] + (float)b[7];
  *reinterpret_cast<float4*>(o) = o0;
  *reinterpret_cast<float4*>(o + 4) = o1;
}

// ---------------- MFMA GEMM, 128x128 tile — R11: R1 loop + data-slab XCD remap -----------------
// K-loop/staging/swizzle byte-identical to R1 (global_load_lds 16B + XOR chunk swizzle,
// 0 bank conflicts, best measured: 39.7us/dispatch).
// R11 change (pure T1): bijective block remap so each XCD (= flat_block_id % 8) owns a DATA SLAB:
//  - modes 1/2: XCD = expert. Expert weights (2MB) + that expert's gathered xb rows (~2MB)
//    both fit the 4MB per-XCD L2 -> A and W fetched ~once (model: default order re-reads
//    all of xb per XCD = 64MB+16MB ~= measured 74MB).
//  - modes 0/3: XCD owns a 4-block by-slab; A panels (1MB) stay hot across the bx sweep.
// Remap is bijective over the launched grid -> correctness independent of actual XCD mapping.
// MODE 0: S(bf16) = silu_pair(xb @ sgut interleaved)  [N=2048 cols -> 1024 via lane pairs]
// MODE 1: H(bf16) = silu(xb[slot_tok] @ w1t[e])
// MODE 2: Y(bf16) = slot_w * (H @ w2t[e])
// MODE 3: out(f32) = sig[m] * (S @ sdt)   (initializes d_out)
template <int MODE>
__global__ __launch_bounds__(256) void gemm_kernel(
    const bf16_t* __restrict__ A, const bf16_t* __restrict__ B, void* __restrict__ Cout,
    int N, const int* __restrict__ offsets, const int* __restrict__ counts,
    const int* __restrict__ slot_tok, const float* __restrict__ slot_w,
    const float* __restrict__ sig) {
  __shared__ bf16_t lds_a[BM * LDK];
  __shared__ bf16_t lds_b[BN * LDK];

  // ---- data-slab XCD remap (bijective) ----
  int bx_l, by_l, e_l;
  {
    const int bx = blockIdx.x, by = blockIdx.y, bz = blockIdx.z;
    if (MODE == 0) {
      const int f = by * 16 + bx;       // gx=16, gy=32
      const int k = f & 7, s = f >> 3;  // XCD k <- by-slab [4k, 4k+4)
      by_l = k * 4 + (s & 3); bx_l = s >> 2; e_l = 0;
    } else if (MODE == 3) {
      const int f = by * 8 + bx;        // gx=8, gy=32
      const int k = f & 7, s = f >> 3;
      by_l = k * 4 + (s & 3); bx_l = s >> 2; e_l = 0;
    } else {
      const int f = (bz * 32 + by) * 8 + bx;  // gx=8, gy=32, gz=8
      e_l = f & 7;                            // XCD <- expert
      const int s = f >> 3;
      by_l = s & 31; bx_l = s >> 5;
    }
  }

  const int e = e_l;
  int m0, mEnd;
  const bf16_t* Bp = B;
  if (MODE == 1 || MODE == 2) {
    const int off = offsets[e], cnt = counts[e];
    m0 = off + by_l * BM;
    mEnd = off + cnt;
    if (m0 >= mEnd) return;
    Bp += (size_t)e * FFN * DMODEL;
  } else {
    m0 = by_l * BM;
    mEnd = N_TOK;
  }
  const int n0 = bx_l * BN;

  const int tid = threadIdx.x;
  const int lane = tid & 63;
  const int wave = tid >> 6;
  const int wm = (wave >> 1) * 64;
  const int wn = (wave & 1) * 64;
  const int qd = lane >> 4;
  const int lm = lane & 15;

  // staging: lane owns row (wave*16 + lane>>2) (+64 for h=1), physical 16B chunk (lane&3);
  // it FETCHES logical chunk (lane&3)^((lane>>3)&3)  [both-sides involution, R6-proven]
  const int srow = wave * 16 + (lane >> 2);
  const int chunk = (lane & 3) ^ ((lane >> 3) & 3);
  const bf16_t* pa[2];
  const bf16_t* pb[2];
#pragma unroll
  for (int h = 0; h < 2; h++) {
    int s = m0 + srow + h * 64;
    int sc = (s < mEnd) ? s : (mEnd - 1);
    int g;
    if (MODE == 1) g = slot_tok[sc];
    else if (MODE == 2) g = sc;
    else g = s;
    pa[h] = A + (size_t)g * 1024 + chunk * 8;  // K = 1024 all modes
    pb[h] = Bp + (size_t)(n0 + srow + h * 64) * 1024 + chunk * 8;
  }
  // wave-uniform LDS bases for the async DMA (dest = base + lane*16B)
  bf16_t* la[2] = {&lds_a[(wave * 16) * LDK], &lds_a[(64 + wave * 16) * LDK]};
  bf16_t* lb[2] = {&lds_b[(wave * 16) * LDK], &lds_b[(64 + wave * 16) * LDK]};

  f32x4 acc[4][4] = {};

  const int rkey = (lm >> 1) & 3;  // read-side swizzle key (bits 1-2 of fragment row)

  for (int k0 = 0; k0 < 1024; k0 += BK) {
    __syncthreads();  // previous-iter reads done before overwrite
#pragma unroll
    for (int h = 0; h < 2; h++) {
      gload16(pa[h] + k0, la[h]);
      gload16(pb[h] + k0, lb[h]);
    }
    __syncthreads();  // vmcnt(0) drained before barrier -> LDS ready
    bf16x8 af[4], bfr[4];
#pragma unroll
    for (int i = 0; i < 4; i++)
      af[i] = *reinterpret_cast<const bf16x8*>(
          &lds_a[(wm + i * 16 + lm) * LDK + ((qd ^ rkey) * 8)]);
#pragma unroll
    for (int j = 0; j < 4; j++)
      bfr[j] = *reinterpret_cast<const bf16x8*>(
          &lds_b[(wn + j * 16 + lm) * LDK + ((qd ^ rkey) * 8)]);
#pragma unroll
    for (int i = 0; i < 4; i++)
#pragma unroll
      for (int j = 0; j < 4; j++)
        acc[i][j] = __builtin_amdgcn_mfma_f32_16x16x32_bf16(af[i], bfr[j], acc[i][j], 0, 0, 0);
  }

  // epilogue: C row = (lane>>4)*4 + reg, col = lane&15  [HW-verified]
#pragma unroll
  for (int i = 0; i < 4; i++) {
#pragma unroll
    for (int r = 0; r < 4; r++) {
      const int gm = m0 + wm + i * 16 + qd * 4 + r;
      const bool mOk = (MODE == 0 || MODE == 3) || (gm < mEnd);
      const float wgt = (MODE == 2 && mOk) ? slot_w[gm] : 0.f;
#pragma unroll
      for (int j = 0; j < 4; j++) {
        const int col = n0 + wn + j * 16 + lm;
        float v = acc[i][j][r];
        if (MODE == 0) {
          // cols interleaved: even = gate f, odd = up f (f = col>>1); pair via shfl_xor
          float u = __shfl_xor(v, 1, 64);
          if ((lane & 1) == 0) {
            float sv = v / (1.f + __expf(-v)) * u;
            ((bf16_t*)Cout)[(size_t)gm * FFN + (col >> 1)] = (bf16_t)sv;
          }
        } else if (MODE == 1) {
          if (mOk) ((bf16_t*)Cout)[(size_t)gm * FFN + col] = (bf16_t)(v / (1.f + __expf(-v)));
        } else if (MODE == 2) {
          if (mOk) ((bf16_t*)Cout)[(size_t)gm * DMODEL + col] = (bf16_t)(wgt * v);
        } else {
          ((float*)Cout)[(size_t)gm * DMODEL + col] = sig[gm] * v;
        }
      }
    }
  }
}

extern "C" void kernel_launch(void* const* d_in, const int* in_sizes, int n_in, void* d_out,
                              int out_size, void* d_ws, size_t ws_size, hipStream_t stream) {
  const float* x = (const float*)d_in[0];
  const float* rw = (const float*)d_in[1];
  const float* w1 = (const float*)d_in[2];
  const float* w2 = (const float*)d_in[3];
  const float* sgu = (const float*)d_in[4];
  const float* sdw = (const float*)d_in[5];
  const float* gw = (const float*)d_in[6];
  float* out = (float*)d_out;

  char* ws = (char*)d_ws;
  size_t off = 0;
  auto alloc = [&](size_t bytes) -> void* {
    void* p = ws + off;
    off += (bytes + 255) & ~(size_t)255;
    return p;
  };
  bf16_t* xb = (bf16_t*)alloc((size_t)N_TOK * DMODEL * 2);
  bf16_t* w1t = (bf16_t*)alloc((size_t)NEXP * DMODEL * FFN * 2);
  bf16_t* w2t = (bf16_t*)alloc((size_t)NEXP * DMODEL * FFN * 2);
  bf16_t* sgut = (bf16_t*)alloc((size_t)2 * FFN * DMODEL * 2);  // rows gate/up interleaved
  bf16_t* sdt = (bf16_t*)alloc((size_t)DMODEL * FFN * 2);
  bf16_t* S = (bf16_t*)alloc((size_t)N_TOK * FFN * 2);
  bf16_t* H = (bf16_t*)alloc((size_t)N_TOK * 2 * FFN * 2);    // slot-major
  bf16_t* Y = (bf16_t*)alloc((size_t)N_TOK * 2 * DMODEL * 2); // slot-major
  int* topi = (int*)alloc(N_TOK * 2 * 4);
  float* topw = (float*)alloc(N_TOK * 2 * 4);
  float* sig = (float*)alloc(N_TOK * 4);
  int* slot_tok = (int*)alloc(N_TOK * 2 * 4);
  float* slot_w = (float*)alloc(N_TOK * 2 * 4);
  int* slot_of = (int*)alloc(N_TOK * 2 * 4);
  int* block_counts = (int*)alloc(HIST_BLK * NEXP * 4);
  int* counts = (int*)alloc(NEXP * 4);
  int* offsets = (int*)alloc(NEXP * 4);

  // prep + routing (R1-proven structure)
  transpose_all_kernel<<<dim3(64, 32, 18), dim3(32, 8), 0, stream>>>(w1, w2, sgu, sdw, w1t, w2t,
                                                                     sgut, sdt);
  router_kernel<<<N_TOK, 64, 0, stream>>>(x, rw, gw, xb, topi, topw, sig);
  hist_kernel<<<HIST_BLK, 256, 0, stream>>>(topi, block_counts);
  gather_kernel<<<HIST_BLK, 256, 0, stream>>>(topi, topw, block_counts, slot_tok, slot_w,
                                              slot_of, offsets, counts);

  // shared up (silu fused into epilogue): S = silu(gate)*up
  gemm_kernel<0><<<dim3(2 * FFN / BN, N_TOK / BM, 1), 256, 0, stream>>>(
      xb, sgut, S, 2 * FFN, nullptr, nullptr, nullptr, nullptr, nullptr);
  // expert up: H = silu(xb[tok] @ w1t[e])
  gemm_kernel<1><<<dim3(FFN / BN, N_TOK / BM, NEXP), 256, 0, stream>>>(
      xb, w1t, H, FFN, offsets, counts, slot_tok, nullptr, nullptr);
  // expert down: Y = slot_w * (H @ w2t[e])
  gemm_kernel<2><<<dim3(DMODEL / BN, N_TOK / BM, NEXP), 256, 0, stream>>>(
      H, w2t, Y, DMODEL, offsets, counts, slot_tok, slot_w, nullptr);
  // shared down: out = sig * (S @ sdt)  (initializes d_out)
  gemm_kernel<3><<<dim3(DMODEL / BN, N_TOK / BM, 1), 256, 0, stream>>>(
      S, sdt, out, DMODEL, nullptr, nullptr, nullptr, nullptr, sig);
  // routed combine
  combine_kernel<<<N_TOK * DMODEL / 8 / 256, 256, 0, stream>>>(Y, slot_of, out);
}

// Round 8
// 277.703 us; speedup vs baseline: 1.3903x; 1.0050x over previous
//
#include <hip/hip_runtime.h>
#include <math.h>

typedef __bf16 bf16_t;
typedef __bf16 bf16x8 __attribute__((ext_vector_type(8)));
typedef __bf16 bf16x4 __attribute__((ext_vector_type(4)));
typedef float f32x4 __attribute__((ext_vector_type(4)));

#define N_TOK 4096
#define DMODEL 1024
#define FFN 1024
#define NEXP 8
#define HIST_BLK 16

#define BM 128
#define BN 128
#define BK 32
#define LDK 32  // linear (global_load_lds needs contiguous dest); conflicts fixed by XOR chunk swizzle

// async global->LDS, 16B per lane, wave-uniform LDS base + lane*16 (ladder step 3)
__device__ __forceinline__ void gload16(const bf16_t* g, bf16_t* l) {
  __builtin_amdgcn_global_load_lds((const __attribute__((address_space(1))) void*)g,
                                   (__attribute__((address_space(3))) void*)l, 16, 0, 0);
}

// ---------------- prep: all weight transposes fp32->bf16 in ONE launch (R3-proven) ----------------
__global__ void transpose_all_kernel(const float* __restrict__ w1, const float* __restrict__ w2,
                                     const float* __restrict__ sgu, const float* __restrict__ sdw,
                                     bf16_t* __restrict__ w1t, bf16_t* __restrict__ w2t,
                                     bf16_t* __restrict__ sgut, bf16_t* __restrict__ sdt) {
  __shared__ float tile[32][33];
  const int z = blockIdx.z;
  const float* in;
  bf16_t* out;
  int C = 1024;
  bool remap = false;
  if (z < 8) {
    in = w1 + (size_t)z * 1048576; out = w1t + (size_t)z * 1048576;
  } else if (z < 16) {
    in = w2 + (size_t)(z - 8) * 1048576; out = w2t + (size_t)(z - 8) * 1048576;
  } else if (z == 16) {
    in = sgu; out = sgut; C = 2048; remap = true;
  } else {
    in = sdw; out = sdt;
  }
  const int R = 1024;
  const int c0 = blockIdx.x * 32, r0 = blockIdx.y * 32;
  if (c0 >= C) return;
  const int tx = threadIdx.x, ty = threadIdx.y;
#pragma unroll
  for (int i = 0; i < 32; i += 8)
    tile[ty + i][tx] = in[(size_t)(r0 + ty + i) * C + (c0 + tx)];
  __syncthreads();
#pragma unroll
  for (int i = 0; i < 32; i += 8) {
    int c = c0 + ty + i;
    int oc = remap ? ((c < FFN) ? 2 * c : 2 * (c - FFN) + 1) : c;
    out[(size_t)oc * R + (r0 + tx)] = (bf16_t)tile[tx][ty + i];
  }
}

// ---------------- router: logits/softmax/top2/sigmoid gate + fused x->bf16 cast ----------------
__global__ void router_kernel(const float* __restrict__ x, const float* __restrict__ rw,
                              const float* __restrict__ gw, bf16_t* __restrict__ xb,
                              int* __restrict__ topi, float* __restrict__ topw,
                              float* __restrict__ sig) {
  const int t = blockIdx.x;
  const int lane = threadIdx.x;  // 64
  const float* xr = x + (size_t)t * DMODEL;
  bf16_t* xbr = xb + (size_t)t * DMODEL;
  float acc[NEXP] = {0.f, 0.f, 0.f, 0.f, 0.f, 0.f, 0.f, 0.f};
  float accg = 0.f;
#pragma unroll
  for (int i = 0; i < 4; i++) {
    const int d = i * 256 + lane * 4;
    float4 xv = *reinterpret_cast<const float4*>(xr + d);
    bf16x4 o;
    o[0] = (bf16_t)xv.x; o[1] = (bf16_t)xv.y; o[2] = (bf16_t)xv.z; o[3] = (bf16_t)xv.w;
    *reinterpret_cast<bf16x4*>(xbr + d) = o;
    const float xs[4] = {xv.x, xv.y, xv.z, xv.w};
#pragma unroll
    for (int j = 0; j < 4; j++) {
      const float4* r = reinterpret_cast<const float4*>(rw + (size_t)(d + j) * NEXP);
      float4 r0 = r[0], r1 = r[1];
      float xj = xs[j];
      acc[0] += xj * r0.x; acc[1] += xj * r0.y; acc[2] += xj * r0.z; acc[3] += xj * r0.w;
      acc[4] += xj * r1.x; acc[5] += xj * r1.y; acc[6] += xj * r1.z; acc[7] += xj * r1.w;
      accg += xj * gw[d + j];
    }
  }
#pragma unroll
  for (int e = 0; e < NEXP; e++)
    for (int s = 32; s > 0; s >>= 1) acc[e] += __shfl_down(acc[e], s, 64);
  for (int s = 32; s > 0; s >>= 1) accg += __shfl_down(accg, s, 64);
  if (lane == 0) {
    float mx = acc[0];
#pragma unroll
    for (int e = 1; e < NEXP; e++) mx = fmaxf(mx, acc[e]);
    float p[NEXP], sum = 0.f;
#pragma unroll
    for (int e = 0; e < NEXP; e++) { p[e] = __expf(acc[e] - mx); sum += p[e]; }
    int i1 = 0;
#pragma unroll
    for (int e = 1; e < NEXP; e++) if (acc[e] > acc[i1]) i1 = e;
    int i2 = (i1 == 0) ? 1 : 0;
#pragma unroll
    for (int e = 0; e < NEXP; e++) if (e != i1 && acc[e] > acc[i2]) i2 = e;
    float inv = 1.f / sum;
    topi[2 * t] = i1;     topw[2 * t] = p[i1] * inv;
    topi[2 * t + 1] = i2; topw[2 * t + 1] = p[i2] * inv;
    sig[t] = 1.f / (1.f + __expf(-accg));
  }
}

// ---------------- per-block expert histogram (LDS only) ----------------
__global__ void hist_kernel(const int* __restrict__ topi, int* __restrict__ block_counts) {
  __shared__ int h[NEXP];
  const int tid = threadIdx.x;
  if (tid < NEXP) h[tid] = 0;
  __syncthreads();
  const int t = blockIdx.x * 256 + tid;
  atomicAdd(&h[topi[2 * t]], 1);
  atomicAdd(&h[topi[2 * t + 1]], 1);
  __syncthreads();
  if (tid < NEXP) block_counts[blockIdx.x * NEXP + tid] = h[tid];
}

// ---------------- gather (scan fused; R5-proven) ----------------
__global__ void gather_kernel(const int* __restrict__ topi, const float* __restrict__ topw,
                              const int* __restrict__ block_counts, int* __restrict__ slot_tok,
                              float* __restrict__ slot_w, int* __restrict__ slot_of,
                              int* __restrict__ offsets, int* __restrict__ counts) {
  __shared__ int cur[NEXP];
  const int tid = threadIdx.x;
  if (tid < NEXP) {
    int off = 0;
    for (int f = 0; f < tid; f++)
      for (int b = 0; b < HIST_BLK; b++) off += block_counts[b * NEXP + f];
    int bb = off;
    for (int b = 0; b < (int)blockIdx.x; b++) bb += block_counts[b * NEXP + tid];
    cur[tid] = bb;
    if (blockIdx.x == 0) {
      offsets[tid] = off;
      int tot = 0;
      for (int b = 0; b < HIST_BLK; b++) tot += block_counts[b * NEXP + tid];
      counts[tid] = tot;
    }
  }
  __syncthreads();
  const int t = blockIdx.x * 256 + tid;
#pragma unroll
  for (int j = 0; j < 2; j++) {
    int e = topi[2 * t + j];
    int s = atomicAdd(&cur[e], 1);
    slot_tok[s] = t;
    slot_w[s] = topw[2 * t + j];
    slot_of[2 * t + j] = s;
  }
}

// ---------------- combine: out[t] += Y[slot0] + Y[slot1] ----------------
__global__ void combine_kernel(const bf16_t* __restrict__ Y, const int* __restrict__ slot_of,
                               float* __restrict__ out) {
  int i = blockIdx.x * blockDim.x + threadIdx.x;
  int t = i >> 7;
  int d = (i & 127) << 3;
  int s0 = slot_of[2 * t], s1 = slot_of[2 * t + 1];
  bf16x8 a = *reinterpret_cast<const bf16x8*>(Y + (size_t)s0 * DMODEL + d);
  bf16x8 b = *reinterpret_cast<const bf16x8*>(Y + (size_t)s1 * DMODEL + d);
  float* o = out + (size_t)t * DMODEL + d;
  float4 o0 = *reinterpret_cast<float4*>(o);
  float4 o1 = *reinterpret_cast<float4*>(o + 4);
  o0.x += (float)a[0] + (float)b[0]; o0.y += (float)a[1] + (float)b[1];
  o0.z += (float)a[2] + (float)b[2]; o0.w += (float)a[3] + (float)b[3];
  o1.x += (float)a[4] + (float)b[4]; o1.y += (float)a[5] + (float)b[5];
  o1.z += (float)a[6] + (float)b[6]; o1.w += (float)a[7] + (float)b[7];
  *reinterpret_cast<float4*>(o) = o0;
  *reinterpret_cast<float4*>(o + 4) = o1;
}

// ---------------- MFMA GEMM, 128x128 tile — R12: slab remap + static-dbuf 2-phase --------------
// R11 slab remap KEPT (win: each XCD owns a data slab; expert GEMMs pin expert weights+rows in
// their XCD's L2). R12 adds the T3 minimal 2-phase done per R8's post-mortem: FOUR statically
// named __shared__ arrays (provable NoAlias -> no premature vmcnt drain), unroll-by-2, plain
// __syncthreads. Per iter: STAGE(next buf) -> COMPUTE(cur buf) -> __syncthreads. The barrier's
// vmcnt(0) drain now lands AFTER ~400cy of MFMA+ds_read, so the (L2-hit, post-R11) prefetch has
// already landed. No inline asm; compiler keeps its own schedule.
// Swizzle (R6-proven involution): phys 16B chunk = logical ^ key; write side key=(lane>>3)&3
// applied to the per-lane GLOBAL source, read side key=(lm>>1)&3. 0 bank conflicts measured.
// MODE 0: S(bf16) = silu_pair(xb @ sgut interleaved)  [N=2048 cols -> 1024 via lane pairs]
// MODE 1: H(bf16) = silu(xb[slot_tok] @ w1t[e])
// MODE 2: Y(bf16) = slot_w * (H @ w2t[e])
// MODE 3: out(f32) = sig[m] * (S @ sdt)   (initializes d_out)
template <int MODE>
__global__ __launch_bounds__(256) void gemm_kernel(
    const bf16_t* __restrict__ A, const bf16_t* __restrict__ B, void* __restrict__ Cout,
    int N, const int* __restrict__ offsets, const int* __restrict__ counts,
    const int* __restrict__ slot_tok, const float* __restrict__ slot_w,
    const float* __restrict__ sig) {
  __shared__ bf16_t lds_a0[BM * LDK];  // 8 KB each, 32 KB total; distinct objects so the
  __shared__ bf16_t lds_b0[BN * LDK];  // waitcnt pass proves DMA-write vs ds_read NoAlias
  __shared__ bf16_t lds_a1[BM * LDK];
  __shared__ bf16_t lds_b1[BN * LDK];

  // ---- data-slab XCD remap (bijective; R11-proven) ----
  int bx_l, by_l, e_l;
  {
    const int bx = blockIdx.x, by = blockIdx.y, bz = blockIdx.z;
    if (MODE == 0) {
      const int f = by * 16 + bx;       // gx=16, gy=32
      const int k = f & 7, s = f >> 3;  // XCD k <- by-slab [4k, 4k+4)
      by_l = k * 4 + (s & 3); bx_l = s >> 2; e_l = 0;
    } else if (MODE == 3) {
      const int f = by * 8 + bx;        // gx=8, gy=32
      const int k = f & 7, s = f >> 3;
      by_l = k * 4 + (s & 3); bx_l = s >> 2; e_l = 0;
    } else {
      const int f = (bz * 32 + by) * 8 + bx;  // gx=8, gy=32, gz=8
      e_l = f & 7;                            // XCD <- expert
      const int s = f >> 3;
      by_l = s & 31; bx_l = s >> 5;
    }
  }

  const int e = e_l;
  int m0, mEnd;
  const bf16_t* Bp = B;
  if (MODE == 1 || MODE == 2) {
    const int off = offsets[e], cnt = counts[e];
    m0 = off + by_l * BM;
    mEnd = off + cnt;
    if (m0 >= mEnd) return;
    Bp += (size_t)e * FFN * DMODEL;
  } else {
    m0 = by_l * BM;
    mEnd = N_TOK;
  }
  const int n0 = bx_l * BN;

  const int tid = threadIdx.x;
  const int lane = tid & 63;
  const int wave = tid >> 6;
  const int wm = (wave >> 1) * 64;
  const int wn = (wave & 1) * 64;
  const int qd = lane >> 4;
  const int lm = lane & 15;

  // staging: lane owns row (wave*16 + lane>>2) (+64 for h=1), physical 16B chunk (lane&3);
  // it FETCHES logical chunk (lane&3)^((lane>>3)&3)  [both-sides involution, R6-proven]
  const int srow = wave * 16 + (lane >> 2);
  const int chunk = (lane & 3) ^ ((lane >> 3) & 3);
  const bf16_t* pa[2];
  const bf16_t* pb[2];
#pragma unroll
  for (int h = 0; h < 2; h++) {
    int s = m0 + srow + h * 64;
    int sc = (s < mEnd) ? s : (mEnd - 1);
    int g;
    if (MODE == 1) g = slot_tok[sc];
    else if (MODE == 2) g = sc;
    else g = s;
    pa[h] = A + (size_t)g * 1024 + chunk * 8;  // K = 1024 all modes
    pb[h] = Bp + (size_t)(n0 + srow + h * 64) * 1024 + chunk * 8;
  }

  f32x4 acc[4][4] = {};
  const int rkey = (lm >> 1) & 3;  // read-side swizzle key (bits 1-2 of fragment row)

  // 4 gload16 per wave per stage (A halves + B halves); dest = wave-uniform base + lane*16B
#define STAGE(AB, BB, T)                                       \
  do {                                                         \
    const int k0s = (T) * BK;                                  \
    gload16(pa[0] + k0s, &AB[(wave * 16) * LDK]);              \
    gload16(pa[1] + k0s, &AB[(64 + wave * 16) * LDK]);         \
    gload16(pb[0] + k0s, &BB[(wave * 16) * LDK]);              \
    gload16(pb[1] + k0s, &BB[(64 + wave * 16) * LDK]);         \
  } while (0)

#define COMPUTE(AB, BB)                                                      \
  do {                                                                       \
    bf16x8 af[4], bfr[4];                                                    \
    _Pragma("unroll") for (int i = 0; i < 4; i++)                            \
        af[i] = *reinterpret_cast<const bf16x8*>(                            \
            &AB[(wm + i * 16 + lm) * LDK + ((qd ^ rkey) * 8)]);              \
    _Pragma("unroll") for (int j = 0; j < 4; j++)                            \
        bfr[j] = *reinterpret_cast<const bf16x8*>(                           \
            &BB[(wn + j * 16 + lm) * LDK + ((qd ^ rkey) * 8)]);              \
    _Pragma("unroll") for (int i = 0; i < 4; i++)                            \
        _Pragma("unroll") for (int j = 0; j < 4; j++)                        \
            acc[i][j] = __builtin_amdgcn_mfma_f32_16x16x32_bf16(             \
                af[i], bfr[j], acc[i][j], 0, 0, 0);                          \
  } while (0)

  // prologue: tile 0 -> buf0
  STAGE(lds_a0, lds_b0, 0);
  __syncthreads();
  // main: stage-next THEN compute-cur; the barrier drain catches loads ~400cy after issue
  for (int t = 0; t < 32; t += 2) {
    STAGE(lds_a1, lds_b1, t + 1);
    COMPUTE(lds_a0, lds_b0);
    __syncthreads();
    if (t + 2 < 32) STAGE(lds_a0, lds_b0, t + 2);
    COMPUTE(lds_a1, lds_b1);
    __syncthreads();
  }
#undef COMPUTE
#undef STAGE

  // epilogue: C row = (lane>>4)*4 + reg, col = lane&15  [HW-verified]
#pragma unroll
  for (int i = 0; i < 4; i++) {
#pragma unroll
    for (int r = 0; r < 4; r++) {
      const int gm = m0 + wm + i * 16 + qd * 4 + r;
      const bool mOk = (MODE == 0 || MODE == 3) || (gm < mEnd);
      const float wgt = (MODE == 2 && mOk) ? slot_w[gm] : 0.f;
#pragma unroll
      for (int j = 0; j < 4; j++) {
        const int col = n0 + wn + j * 16 + lm;
        float v = acc[i][j][r];
        if (MODE == 0) {
          // cols interleaved: even = gate f, odd = up f (f = col>>1); pair via shfl_xor
          float u = __shfl_xor(v, 1, 64);
          if ((lane & 1) == 0) {
            float sv = v / (1.f + __expf(-v)) * u;
            ((bf16_t*)Cout)[(size_t)gm * FFN + (col >> 1)] = (bf16_t)sv;
          }
        } else if (MODE == 1) {
          if (mOk) ((bf16_t*)Cout)[(size_t)gm * FFN + col] = (bf16_t)(v / (1.f + __expf(-v)));
        } else if (MODE == 2) {
          if (mOk) ((bf16_t*)Cout)[(size_t)gm * DMODEL + col] = (bf16_t)(wgt * v);
        } else {
          ((float*)Cout)[(size_t)gm * DMODEL + col] = sig[gm] * v;
        }
      }
    }
  }
}

extern "C" void kernel_launch(void* const* d_in, const int* in_sizes, int n_in, void* d_out,
                              int out_size, void* d_ws, size_t ws_size, hipStream_t stream) {
  const float* x = (const float*)d_in[0];
  const float* rw = (const float*)d_in[1];
  const float* w1 = (const float*)d_in[2];
  const float* w2 = (const float*)d_in[3];
  const float* sgu = (const float*)d_in[4];
  const float* sdw = (const float*)d_in[5];
  const float* gw = (const float*)d_in[6];
  float* out = (float*)d_out;

  char* ws = (char*)d_ws;
  size_t off = 0;
  auto alloc = [&](size_t bytes) -> void* {
    void* p = ws + off;
    off += (bytes + 255) & ~(size_t)255;
    return p;
  };
  bf16_t* xb = (bf16_t*)alloc((size_t)N_TOK * DMODEL * 2);
  bf16_t* w1t = (bf16_t*)alloc((size_t)NEXP * DMODEL * FFN * 2);
  bf16_t* w2t = (bf16_t*)alloc((size_t)NEXP * DMODEL * FFN * 2);
  bf16_t* sgut = (bf16_t*)alloc((size_t)2 * FFN * DMODEL * 2);  // rows gate/up interleaved
  bf16_t* sdt = (bf16_t*)alloc((size_t)DMODEL * FFN * 2);
  bf16_t* S = (bf16_t*)alloc((size_t)N_TOK * FFN * 2);
  bf16_t* H = (bf16_t*)alloc((size_t)N_TOK * 2 * FFN * 2);    // slot-major
  bf16_t* Y = (bf16_t*)alloc((size_t)N_TOK * 2 * DMODEL * 2); // slot-major
  int* topi = (int*)alloc(N_TOK * 2 * 4);
  float* topw = (float*)alloc(N_TOK * 2 * 4);
  float* sig = (float*)alloc(N_TOK * 4);
  int* slot_tok = (int*)alloc(N_TOK * 2 * 4);
  float* slot_w = (float*)alloc(N_TOK * 2 * 4);
  int* slot_of = (int*)alloc(N_TOK * 2 * 4);
  int* block_counts = (int*)alloc(HIST_BLK * NEXP * 4);
  int* counts = (int*)alloc(NEXP * 4);
  int* offsets = (int*)alloc(NEXP * 4);

  // prep + routing (R1-proven structure)
  transpose_all_kernel<<<dim3(64, 32, 18), dim3(32, 8), 0, stream>>>(w1, w2, sgu, sdw, w1t, w2t,
                                                                     sgut, sdt);
  router_kernel<<<N_TOK, 64, 0, stream>>>(x, rw, gw, xb, topi, topw, sig);
  hist_kernel<<<HIST_BLK, 256, 0, stream>>>(topi, block_counts);
  gather_kernel<<<HIST_BLK, 256, 0, stream>>>(topi, topw, block_counts, slot_tok, slot_w,
                                              slot_of, offsets, counts);

  // shared up (silu fused into epilogue): S = silu(gate)*up
  gemm_kernel<0><<<dim3(2 * FFN / BN, N_TOK / BM, 1), 256, 0, stream>>>(
      xb, sgut, S, 2 * FFN, nullptr, nullptr, nullptr, nullptr, nullptr);
  // expert up: H = silu(xb[tok] @ w1t[e])
  gemm_kernel<1><<<dim3(FFN / BN, N_TOK / BM, NEXP), 256, 0, stream>>>(
      xb, w1t, H, FFN, offsets, counts, slot_tok, nullptr, nullptr);
  // expert down: Y = slot_w * (H @ w2t[e])
  gemm_kernel<2><<<dim3(DMODEL / BN, N_TOK / BM, NEXP), 256, 0, stream>>>(
      H, w2t, Y, DMODEL, offsets, counts, slot_tok, slot_w, nullptr);
  // shared down: out = sig * (S @ sdt)  (initializes d_out)
  gemm_kernel<3><<<dim3(DMODEL / BN, N_TOK / BM, 1), 256, 0, stream>>>(
      S, sdt, out, DMODEL, nullptr, nullptr, nullptr, nullptr, sig);
  // routed combine
  combine_kernel<<<N_TOK * DMODEL / 8 / 256, 256, 0, stream>>>(Y, slot_of, out);
}